// Round 1
// baseline (88.029 us; speedup 1.0000x reference)
//
#include <hip/hip_runtime.h>

// ConcatenationAttention: B=8, S=1024, H=128, A=16
// out[b,i,:] = sum_{j<i} w_ij * x[b,j,:],  w = softmax over j of
//   score(i,j) = sum_a w2[a]*tanh(f[b,i,a] + g[b,j,a] + b1[a]) + b2
// f = x @ W1[:H], g = x @ W1[H:]
//
// Kernel A: f2 = (f + b1) * 2log2e, g2 = g * 2log2e  (pre-scaled for exp2-tanh)
// Kernel B: per (b, 16-row i-tile): loop 64-j chunks, stage x/g in LDS,
//   e = exp2(K - sum_a w2s[a]*rcp(exp2(f2+g2)+1)), register-tiled PV.

#define B_ 8
#define S_ 1024
#define H_ 128
#define A_ 16
#define TI 16
#define JC 64

__global__ __launch_bounds__(256) void fg_kernel(
    const float* __restrict__ x, const float* __restrict__ W1,
    const float* __restrict__ b1, float* __restrict__ f2,
    float* __restrict__ g2) {
  int gid = blockIdx.x * 256 + threadIdx.x;   // B*S*32 threads
  int row = gid >> 5;                         // b*S + s
  int q = gid & 31;
  int a = q & 15;
  int half = q >> 4;
  const float4* x4 = reinterpret_cast<const float4*>(x + (size_t)row * H_);
  const float* w = W1 + half * H_ * A_ + a;   // column a, stride A_
  float s = 0.f;
#pragma unroll 4
  for (int hi = 0; hi < H_ / 4; ++hi) {
    float4 xv = x4[hi];
    s = fmaf(xv.x, w[(hi * 4 + 0) * A_], s);
    s = fmaf(xv.y, w[(hi * 4 + 1) * A_], s);
    s = fmaf(xv.z, w[(hi * 4 + 2) * A_], s);
    s = fmaf(xv.w, w[(hi * 4 + 3) * A_], s);
  }
  const float TANH_C = 2.8853900817779268f;   // 2*log2(e)
  if (half == 0)
    f2[row * A_ + a] = (s + b1[a]) * TANH_C;  // fold b1 into f
  else
    g2[row * A_ + a] = s * TANH_C;
}

__global__ __launch_bounds__(256) void attn_kernel(
    const float* __restrict__ x, const float* __restrict__ f2,
    const float* __restrict__ g2, const float* __restrict__ w2,
    const float* __restrict__ b2, float* __restrict__ out) {
  __shared__ __align__(16) float xs[JC * H_];   // 32 KB; also reduce scratch
  __shared__ __align__(16) float gsm[JC * 18];  // pad 16->18: conflict-free
  __shared__ __align__(16) float es[JC * A_];   // e[j_local][ti]
  __shared__ float dpart[4][16];
  __shared__ float denom[TI];

  const int tid = threadIdx.x;
  const int bid = blockIdx.x;
  const int tile = (S_ / TI - 1) - (bid >> 3);  // heavy tiles dispatched first
  const int b = bid & 7;
  const int i0 = tile * TI;

  const float LOG2E = 1.4426950408889634f;
  float w2s[16];
  float K;
  {
    float sw = 0.f;
#pragma unroll
    for (int a = 0; a < 16; ++a) {
      float v = w2[a];
      w2s[a] = v * (2.f * LOG2E);
      sw += v;
    }
    K = (sw + b2[0]) * LOG2E;  // (sum w2 + b2) * log2e
  }

  const int ti_e = tid & 15;   // score-phase: i row within tile
  const int jq = tid >> 4;     // score-phase: j quad
  float f_reg[16];
  {
    const float* frow = f2 + (size_t)((b << 10) + i0 + ti_e) * A_;
#pragma unroll
    for (int a = 0; a < 16; ++a) f_reg[a] = frow[a];
  }

  const int hc = tid & 31;     // PV: h column group (4 floats)
  const int jg = tid >> 5;     // PV: j partition (8 groups)
  float4 acc[TI];
#pragma unroll
  for (int t = 0; t < TI; ++t) acc[t] = make_float4(0.f, 0.f, 0.f, 0.f);
  if (tid < TI) denom[tid] = 0.f;

  const int nch = (i0 + TI - 1 + JC - 1) / JC;  // j < i0+TI-1 needed at most
  float4* xs4 = reinterpret_cast<float4*>(xs);
  const float4* es4 = reinterpret_cast<const float4*>(es);
  const float4* xg4 = reinterpret_cast<const float4*>(x + (size_t)(b << 10) * H_);

  for (int c = 0; c < nch; ++c) {
    const int jbase = c * JC;
    __syncthreads();  // protect xs/gsm/es/dpart from previous iteration
    // stage x chunk: 64 rows x 128 f = 2048 float4
    const float4* src = xg4 + jbase * (H_ / 4);
#pragma unroll
    for (int t = 0; t < 8; ++t) xs4[tid + 256 * t] = src[tid + 256 * t];
    // stage g chunk into padded [64][18]
    {
      const float4* g4p =
          reinterpret_cast<const float4*>(g2 + (size_t)((b << 10) + jbase) * A_);
      float4 g4 = g4p[tid];
      float* dst = gsm + (tid >> 2) * 18 + (tid & 3) * 4;
      dst[0] = g4.x; dst[1] = g4.y; dst[2] = g4.z; dst[3] = g4.w;
    }
    __syncthreads();

    // ---- score phase: e[jl][ti] for 16 ti x 64 j, 4 pairs/thread ----
    float partial = 0.f;
#pragma unroll
    for (int k = 0; k < 4; ++k) {
      const int jl = jq * 4 + k;
      const int j = jbase + jl;
      const float* grow = gsm + jl * 18;
      float ps = 0.f;
#pragma unroll
      for (int a = 0; a < 16; ++a) {
        float E = exp2f(f_reg[a] + grow[a]);          // e^{2(f+g+b1)}
        float r = __builtin_amdgcn_rcpf(E + 1.0f);
        ps = fmaf(w2s[a], r, ps);                     // sum w2*2log2e*r
      }
      // score*log2e = K - ps ; mask j < i
      float ev = (j < i0 + ti_e) ? exp2f(K - ps) : 0.f;
      es[jl * A_ + ti_e] = ev;
      partial += ev;
    }
    // denom: sum over j. partial holds 4 j's for (ti_e). Reduce jq groups.
    partial += __shfl_xor(partial, 16);
    partial += __shfl_xor(partial, 32);
    if ((tid & 63) < 16) dpart[tid >> 6][ti_e] = partial;
    __syncthreads();
    if (tid < 16)
      denom[tid] += dpart[0][tid] + dpart[1][tid] + dpart[2][tid] + dpart[3][tid];

    // ---- PV phase: acc[ti][4h] += e[ti][j] * x[j][4h], 8 j per thread ----
#pragma unroll 2
    for (int jj = 0; jj < 8; ++jj) {
      const int jl = jg * 8 + jj;
      float4 xv = xs4[jl * (H_ / 4) + hc];
      float4 e0 = es4[jl * 4 + 0];
      float4 e1 = es4[jl * 4 + 1];
      float4 e2 = es4[jl * 4 + 2];
      float4 e3 = es4[jl * 4 + 3];
#define FMA4_(AC, sc)                \
  AC.x = fmaf(sc, xv.x, AC.x);       \
  AC.y = fmaf(sc, xv.y, AC.y);       \
  AC.z = fmaf(sc, xv.z, AC.z);       \
  AC.w = fmaf(sc, xv.w, AC.w)
      FMA4_(acc[0], e0.x);  FMA4_(acc[1], e0.y);
      FMA4_(acc[2], e0.z);  FMA4_(acc[3], e0.w);
      FMA4_(acc[4], e1.x);  FMA4_(acc[5], e1.y);
      FMA4_(acc[6], e1.z);  FMA4_(acc[7], e1.w);
      FMA4_(acc[8], e2.x);  FMA4_(acc[9], e2.y);
      FMA4_(acc[10], e2.z); FMA4_(acc[11], e2.w);
      FMA4_(acc[12], e3.x); FMA4_(acc[13], e3.y);
      FMA4_(acc[14], e3.z); FMA4_(acc[15], e3.w);
#undef FMA4_
    }
  }

  // ---- cross-jg tree reduce (8 -> 1) using xs as scratch ----
  __syncthreads();
  float4* red4 = xs4;
  if (jg >= 4) {
#pragma unroll
    for (int t = 0; t < TI; ++t) red4[((jg - 4) * TI + t) * 32 + hc] = acc[t];
  }
  __syncthreads();
  if (jg < 4) {
#pragma unroll
    for (int t = 0; t < TI; ++t) {
      float4 v = red4[(jg * TI + t) * 32 + hc];
      acc[t].x += v.x; acc[t].y += v.y; acc[t].z += v.z; acc[t].w += v.w;
    }
  }
  __syncthreads();
  if (jg == 2 || jg == 3) {
#pragma unroll
    for (int t = 0; t < TI; ++t) red4[((jg - 2) * TI + t) * 32 + hc] = acc[t];
  }
  __syncthreads();
  if (jg < 2) {
#pragma unroll
    for (int t = 0; t < TI; ++t) {
      float4 v = red4[(jg * TI + t) * 32 + hc];
      acc[t].x += v.x; acc[t].y += v.y; acc[t].z += v.z; acc[t].w += v.w;
    }
  }
  __syncthreads();
  if (jg == 1) {
#pragma unroll
    for (int t = 0; t < TI; ++t) red4[t * 32 + hc] = acc[t];
  }
  __syncthreads();
  if (jg == 0) {
    float4* out4 = reinterpret_cast<float4*>(out);
#pragma unroll
    for (int t = 0; t < TI; ++t) {
      float4 v = red4[t * 32 + hc];
      float dn = 1.0f / (denom[t] + 1e-10f);
      float4 o;
      o.x = (acc[t].x + v.x) * dn;
      o.y = (acc[t].y + v.y) * dn;
      o.z = (acc[t].z + v.z) * dn;
      o.w = (acc[t].w + v.w) * dn;
      out4[(size_t)((b << 10) + i0 + t) * 32 + hc] = o;
    }
  }
}

extern "C" void kernel_launch(void* const* d_in, const int* in_sizes, int n_in,
                              void* d_out, int out_size, void* d_ws,
                              size_t ws_size, hipStream_t stream) {
  (void)in_sizes; (void)n_in; (void)out_size; (void)ws_size;
  const float* x  = (const float*)d_in[0];
  const float* W1 = (const float*)d_in[1];
  const float* b1 = (const float*)d_in[2];
  const float* w2 = (const float*)d_in[3];
  const float* b2 = (const float*)d_in[4];
  float* out = (float*)d_out;
  float* f2 = (float*)d_ws;                 // [B*S, A] pre-scaled f + b1
  float* g2 = f2 + (size_t)B_ * S_ * A_;    // [B*S, A] pre-scaled g

  fg_kernel<<<(B_ * S_ * 32) / 256, 256, 0, stream>>>(x, W1, b1, f2, g2);
  attn_kernel<<<B_ * (S_ / TI), 256, 0, stream>>>(x, f2, g2, w2, b2, out);
}

// Round 2
// 86.875 us; speedup vs baseline: 1.0133x; 1.0133x over previous
//
#include <hip/hip_runtime.h>

// ConcatenationAttention: B=8, S=1024, H=128, A=16
// out[b,i,:] = sum_{j<i} w_ij * x[b,j,:],  w = softmax over j of
//   score(i,j) = sum_a w2[a]*tanh(f[b,i,a] + g[b,j,a] + b1[a]) + b2
//
// Round 2: segmented j-range (256-wide) -> 1280 equal blocks, partials in ws,
// combine kernel. No x/g LDS staging (no intra-block reuse after j-split;
// L2-resident). 4-way j-partition PV -> acc[8]xfloat4 = 32 VGPR.

#define B_ 8
#define S_ 1024
#define H_ 128
#define A_ 16
#define TI 16
#define JC 64

__global__ __launch_bounds__(256) void fg_kernel(
    const float* __restrict__ x, const float* __restrict__ W1,
    const float* __restrict__ b1, float* __restrict__ f2,
    float* __restrict__ g2) {
  int gid = blockIdx.x * 256 + threadIdx.x;   // B*S*32 threads
  int row = gid >> 5;                         // b*S + s
  int q = gid & 31;
  int a = q & 15;
  int half = q >> 4;
  const float4* x4 = reinterpret_cast<const float4*>(x + (size_t)row * H_);
  const float* w = W1 + half * H_ * A_ + a;   // column a, stride A_
  float s = 0.f;
#pragma unroll 4
  for (int hi = 0; hi < H_ / 4; ++hi) {
    float4 xv = x4[hi];
    s = fmaf(xv.x, w[(hi * 4 + 0) * A_], s);
    s = fmaf(xv.y, w[(hi * 4 + 1) * A_], s);
    s = fmaf(xv.z, w[(hi * 4 + 2) * A_], s);
    s = fmaf(xv.w, w[(hi * 4 + 3) * A_], s);
  }
  const float TANH_C = 2.8853900817779268f;   // 2*log2(e)
  if (half == 0)
    f2[row * A_ + a] = (s + b1[a]) * TANH_C;  // fold b1 into f
  else
    g2[row * A_ + a] = s * TANH_C;
}

// ---------------- segmented attention partial ----------------
// grid: B_ * 160 blocks. Per-b segment index sidx in [0,160):
// tiles 0-15: 1 seg, 16-31: 2, 32-47: 3, 48-63: 4 segs of 256 j each.
__global__ __launch_bounds__(256, 4) void attn_part(
    const float* __restrict__ x, const float* __restrict__ f2,
    const float* __restrict__ g2, const float* __restrict__ w2,
    const float* __restrict__ b2, float* __restrict__ pacc,
    float* __restrict__ pden) {
  __shared__ __align__(16) float es[JC * A_];   // e[jl][ti], 4 KB
  __shared__ __align__(16) float4 red4[1024];   // 16 KB tree scratch
  __shared__ float dpart[4][16];
  __shared__ float denom[TI];

  const int tid = threadIdx.x;
  const int bid = blockIdx.x;
  const int b = bid / 160;
  const int sidx = bid - b * 160;
  int t, s;
  if (sidx < 16)      { t = sidx;                                  s = 0; }
  else if (sidx < 48) { int u = sidx - 16; t = 16 + (u >> 1);      s = u & 1; }
  else if (sidx < 96) { int u = sidx - 48; t = 32 + u / 3;         s = u - (t - 32) * 3; }
  else                { int u = sidx - 96; t = 48 + (u >> 2);      s = u & 3; }
  const int i0 = t << 4;
  const int jbase0 = s << 8;
  const int nch = min(4, (i0 + 15 - jbase0 + 63) >> 6);
  const int slot = (((b << 6) + t) << 2) + s;

  const float LOG2E = 1.4426950408889634f;
  float w2s[16];
  float K;
  {
    float sw = 0.f;
#pragma unroll
    for (int a = 0; a < 16; ++a) {
      float v = w2[a];
      w2s[a] = v * (2.f * LOG2E);
      sw += v;
    }
    K = (sw + b2[0]) * LOG2E;
  }

  // score-phase mapping
  const int ti_e = tid & 15;
  const int jq = tid >> 4;           // [0,16): 4 j's each
  float f_reg[16];
  {
    const float* frow = f2 + (size_t)((b << 10) + i0 + ti_e) * A_;
#pragma unroll
    for (int a = 0; a < 16; ++a) f_reg[a] = frow[a];
  }

  // PV mapping: 4 j-partitions (1 wave each); lane owns (th,hq): ti=th*8+k
  const int part = tid >> 6;
  const int lane = tid & 63;
  const int hq = lane & 31;          // float4 column
  const int th = lane >> 5;          // ti half
  float4 acc[8];
#pragma unroll
  for (int k = 0; k < 8; ++k) acc[k] = make_float4(0.f, 0.f, 0.f, 0.f);
  if (tid < TI) denom[tid] = 0.f;

  const float4* xb4 = reinterpret_cast<const float4*>(x + (size_t)(b << 10) * H_);
  const float4* es4 = reinterpret_cast<const float4*>(es);

  for (int c = 0; c < nch; ++c) {
    const int jbase = jbase0 + (c << 6);
    __syncthreads();  // es/dpart reusable

    // ---- score phase: e[jl][ti], 4 j per thread ----
    float partial = 0.f;
#pragma unroll
    for (int k = 0; k < 4; ++k) {
      const int jl = (jq << 2) + k;
      const int j = jbase + jl;
      const float4* grow4 =
          reinterpret_cast<const float4*>(g2 + (size_t)((b << 10) + j) * A_);
      float4 ga0 = grow4[0], ga1 = grow4[1], ga2 = grow4[2], ga3 = grow4[3];
      float gv[16] = {ga0.x, ga0.y, ga0.z, ga0.w, ga1.x, ga1.y, ga1.z, ga1.w,
                      ga2.x, ga2.y, ga2.z, ga2.w, ga3.x, ga3.y, ga3.z, ga3.w};
      float ps = 0.f;
#pragma unroll
      for (int a = 0; a < 16; ++a) {
        float E = exp2f(f_reg[a] + gv[a]);            // e^{2(f+g+b1)}
        float r = __builtin_amdgcn_rcpf(E + 1.0f);
        ps = fmaf(w2s[a], r, ps);
      }
      float ev = (j < i0 + ti_e) ? exp2f(K - ps) : 0.f;
      es[jl * A_ + ti_e] = ev;
      partial += ev;
    }
    partial += __shfl_xor(partial, 16);
    partial += __shfl_xor(partial, 32);
    if ((tid & 63) < 16) dpart[tid >> 6][ti_e] = partial;
    __syncthreads();
    if (tid < 16)
      denom[tid] += dpart[0][tid] + dpart[1][tid] + dpart[2][tid] + dpart[3][tid];

    // ---- PV: acc[k] += e[ti][j] * x[j][hq], 16 j per thread, x from L2 ----
#pragma unroll 4
    for (int jj = 0; jj < 16; ++jj) {
      const int jl = (part << 4) + jj;
      const int j = jbase + jl;
      float4 xv = xb4[(size_t)j * 32 + hq];
      float4 e0 = es4[jl * 4 + (th << 1)];
      float4 e1 = es4[jl * 4 + (th << 1) + 1];
#define FMA4_(AC, sc)                \
  AC.x = fmaf(sc, xv.x, AC.x);       \
  AC.y = fmaf(sc, xv.y, AC.y);       \
  AC.z = fmaf(sc, xv.z, AC.z);       \
  AC.w = fmaf(sc, xv.w, AC.w)
      FMA4_(acc[0], e0.x); FMA4_(acc[1], e0.y);
      FMA4_(acc[2], e0.z); FMA4_(acc[3], e0.w);
      FMA4_(acc[4], e1.x); FMA4_(acc[5], e1.y);
      FMA4_(acc[6], e1.z); FMA4_(acc[7], e1.w);
#undef FMA4_
    }
  }

  // ---- cross-partition tree reduce (4 -> 1) ----
  __syncthreads();
  if (part >= 2) {
#pragma unroll
    for (int k = 0; k < 8; ++k)
      red4[((part - 2) << 9) + (lane << 3) + k] = acc[k];
  }
  __syncthreads();
  if (part < 2) {
#pragma unroll
    for (int k = 0; k < 8; ++k) {
      float4 v = red4[(part << 9) + (lane << 3) + k];
      acc[k].x += v.x; acc[k].y += v.y; acc[k].z += v.z; acc[k].w += v.w;
    }
  }
  __syncthreads();
  if (part == 1) {
#pragma unroll
    for (int k = 0; k < 8; ++k) red4[(lane << 3) + k] = acc[k];
  }
  __syncthreads();
  if (part == 0) {
    float4* pacc4 = reinterpret_cast<float4*>(pacc);
#pragma unroll
    for (int k = 0; k < 8; ++k) {
      float4 v = red4[(lane << 3) + k];
      float4 o;
      o.x = acc[k].x + v.x; o.y = acc[k].y + v.y;
      o.z = acc[k].z + v.z; o.w = acc[k].w + v.w;
      pacc4[(size_t)slot * 512 + (size_t)((th << 3) + k) * 32 + hq] = o;
    }
  }
  if (tid < 16) pden[slot * 16 + tid] = denom[tid];
}

__global__ __launch_bounds__(256) void combine_kernel(
    const float* __restrict__ pacc, const float* __restrict__ pden,
    float* __restrict__ out) {
  const int gid = blockIdx.x * 256 + threadIdx.x;  // B*S*32
  const int row = gid >> 5;
  const int hq = gid & 31;
  const int i = row & 1023;
  const int t = i >> 4;
  const int nseg = (t >> 4) + 1;
  const int slotbase = ((row >> 10) << 8) + (t << 2);  // ((b<<6)+t)<<2
  const float4* pacc4 = reinterpret_cast<const float4*>(pacc);
  float4 sum = make_float4(0.f, 0.f, 0.f, 0.f);
  float den = 0.f;
  for (int s = 0; s < nseg; ++s) {
    const int slot = slotbase + s;
    float4 v = pacc4[(size_t)slot * 512 + (size_t)(i & 15) * 32 + hq];
    sum.x += v.x; sum.y += v.y; sum.z += v.z; sum.w += v.w;
    den += pden[slot * 16 + (i & 15)];
  }
  const float dn = 1.0f / (den + 1e-10f);
  float4 o;
  o.x = sum.x * dn; o.y = sum.y * dn; o.z = sum.z * dn; o.w = sum.w * dn;
  reinterpret_cast<float4*>(out)[(size_t)row * 32 + hq] = o;
}

// ---------------- fallback: round-1 monolithic kernel ----------------
__global__ __launch_bounds__(256) void attn_kernel_mono(
    const float* __restrict__ x, const float* __restrict__ f2,
    const float* __restrict__ g2, const float* __restrict__ w2,
    const float* __restrict__ b2, float* __restrict__ out) {
  __shared__ __align__(16) float xs[JC * H_];
  __shared__ __align__(16) float gsm[JC * 18];
  __shared__ __align__(16) float es[JC * A_];
  __shared__ float dpart[4][16];
  __shared__ float denom[TI];

  const int tid = threadIdx.x;
  const int bid = blockIdx.x;
  const int tile = (S_ / TI - 1) - (bid >> 3);
  const int b = bid & 7;
  const int i0 = tile * TI;

  const float LOG2E = 1.4426950408889634f;
  float w2s[16];
  float K;
  {
    float sw = 0.f;
#pragma unroll
    for (int a = 0; a < 16; ++a) {
      float v = w2[a];
      w2s[a] = v * (2.f * LOG2E);
      sw += v;
    }
    K = (sw + b2[0]) * LOG2E;
  }

  const int ti_e = tid & 15;
  const int jq = tid >> 4;
  float f_reg[16];
  {
    const float* frow = f2 + (size_t)((b << 10) + i0 + ti_e) * A_;
#pragma unroll
    for (int a = 0; a < 16; ++a) f_reg[a] = frow[a];
  }

  const int hc = tid & 31;
  const int jg = tid >> 5;
  float4 acc[TI];
#pragma unroll
  for (int t = 0; t < TI; ++t) acc[t] = make_float4(0.f, 0.f, 0.f, 0.f);
  if (tid < TI) denom[tid] = 0.f;

  const int nch = (i0 + TI - 1 + JC - 1) / JC;
  float4* xs4 = reinterpret_cast<float4*>(xs);
  const float4* es4 = reinterpret_cast<const float4*>(es);
  const float4* xg4 = reinterpret_cast<const float4*>(x + (size_t)(b << 10) * H_);

  for (int c = 0; c < nch; ++c) {
    const int jbase = c * JC;
    __syncthreads();
    const float4* src = xg4 + jbase * (H_ / 4);
#pragma unroll
    for (int t = 0; t < 8; ++t) xs4[tid + 256 * t] = src[tid + 256 * t];
    {
      const float4* g4p =
          reinterpret_cast<const float4*>(g2 + (size_t)((b << 10) + jbase) * A_);
      float4 g4 = g4p[tid];
      float* dst = gsm + (tid >> 2) * 18 + (tid & 3) * 4;
      dst[0] = g4.x; dst[1] = g4.y; dst[2] = g4.z; dst[3] = g4.w;
    }
    __syncthreads();

    float partial = 0.f;
#pragma unroll
    for (int k = 0; k < 4; ++k) {
      const int jl = jq * 4 + k;
      const int j = jbase + jl;
      const float* grow = gsm + jl * 18;
      float ps = 0.f;
#pragma unroll
      for (int a = 0; a < 16; ++a) {
        float E = exp2f(f_reg[a] + grow[a]);
        float r = __builtin_amdgcn_rcpf(E + 1.0f);
        ps = fmaf(w2s[a], r, ps);
      }
      float ev = (j < i0 + ti_e) ? exp2f(K - ps) : 0.f;
      es[jl * A_ + ti_e] = ev;
      partial += ev;
    }
    partial += __shfl_xor(partial, 16);
    partial += __shfl_xor(partial, 32);
    if ((tid & 63) < 16) dpart[tid >> 6][ti_e] = partial;
    __syncthreads();
    if (tid < 16)
      denom[tid] += dpart[0][tid] + dpart[1][tid] + dpart[2][tid] + dpart[3][tid];

#pragma unroll 2
    for (int jj = 0; jj < 8; ++jj) {
      const int jl = jg * 8 + jj;
      float4 xv = xs4[jl * (H_ / 4) + hc];
      float4 e0 = es4[jl * 4 + 0];
      float4 e1 = es4[jl * 4 + 1];
      float4 e2 = es4[jl * 4 + 2];
      float4 e3 = es4[jl * 4 + 3];
#define FMA4_(AC, sc)                \
  AC.x = fmaf(sc, xv.x, AC.x);       \
  AC.y = fmaf(sc, xv.y, AC.y);       \
  AC.z = fmaf(sc, xv.z, AC.z);       \
  AC.w = fmaf(sc, xv.w, AC.w)
      FMA4_(acc[0], e0.x);  FMA4_(acc[1], e0.y);
      FMA4_(acc[2], e0.z);  FMA4_(acc[3], e0.w);
      FMA4_(acc[4], e1.x);  FMA4_(acc[5], e1.y);
      FMA4_(acc[6], e1.z);  FMA4_(acc[7], e1.w);
      FMA4_(acc[8], e2.x);  FMA4_(acc[9], e2.y);
      FMA4_(acc[10], e2.z); FMA4_(acc[11], e2.w);
      FMA4_(acc[12], e3.x); FMA4_(acc[13], e3.y);
      FMA4_(acc[14], e3.z); FMA4_(acc[15], e3.w);
#undef FMA4_
    }
  }

  __syncthreads();
  float4* red4 = xs4;
  if (jg >= 4) {
#pragma unroll
    for (int t = 0; t < TI; ++t) red4[((jg - 4) * TI + t) * 32 + hc] = acc[t];
  }
  __syncthreads();
  if (jg < 4) {
#pragma unroll
    for (int t = 0; t < TI; ++t) {
      float4 v = red4[(jg * TI + t) * 32 + hc];
      acc[t].x += v.x; acc[t].y += v.y; acc[t].z += v.z; acc[t].w += v.w;
    }
  }
  __syncthreads();
  if (jg == 2 || jg == 3) {
#pragma unroll
    for (int t = 0; t < TI; ++t) red4[((jg - 2) * TI + t) * 32 + hc] = acc[t];
  }
  __syncthreads();
  if (jg < 2) {
#pragma unroll
    for (int t = 0; t < TI; ++t) {
      float4 v = red4[(jg * TI + t) * 32 + hc];
      acc[t].x += v.x; acc[t].y += v.y; acc[t].z += v.z; acc[t].w += v.w;
    }
  }
  __syncthreads();
  if (jg == 1) {
#pragma unroll
    for (int t = 0; t < TI; ++t) red4[t * 32 + hc] = acc[t];
  }
  __syncthreads();
  if (jg == 0) {
    float4* out4 = reinterpret_cast<float4*>(out);
#pragma unroll
    for (int t = 0; t < TI; ++t) {
      float4 v = red4[t * 32 + hc];
      float dn = 1.0f / (denom[t] + 1e-10f);
      float4 o;
      o.x = (acc[t].x + v.x) * dn;
      o.y = (acc[t].y + v.y) * dn;
      o.z = (acc[t].z + v.z) * dn;
      o.w = (acc[t].w + v.w) * dn;
      out4[(size_t)((b << 10) + i0 + t) * 32 + hc] = o;
    }
  }
}

extern "C" void kernel_launch(void* const* d_in, const int* in_sizes, int n_in,
                              void* d_out, int out_size, void* d_ws,
                              size_t ws_size, hipStream_t stream) {
  (void)in_sizes; (void)n_in; (void)out_size;
  const float* x  = (const float*)d_in[0];
  const float* W1 = (const float*)d_in[1];
  const float* b1 = (const float*)d_in[2];
  const float* w2 = (const float*)d_in[3];
  const float* b2 = (const float*)d_in[4];
  float* out = (float*)d_out;

  float* f2 = (float*)d_ws;                  // [B*S, A]
  float* g2 = f2 + (size_t)B_ * S_ * A_;     // [B*S, A]
  float* pacc = g2 + (size_t)B_ * S_ * A_;   // [2048 slots][16][128]
  float* pden = pacc + (size_t)2048 * 2048;  // [2048 slots][16]

  const size_t need_bytes =
      ((size_t)B_ * S_ * A_ * 2 + (size_t)2048 * 2048 + (size_t)2048 * 16) *
      sizeof(float);

  fg_kernel<<<(B_ * S_ * 32) / 256, 256, 0, stream>>>(x, W1, b1, f2, g2);
  if (ws_size >= need_bytes) {
    attn_part<<<B_ * 160, 256, 0, stream>>>(x, f2, g2, w2, b2, pacc, pden);
    combine_kernel<<<(B_ * S_ * 32) / 256, 256, 0, stream>>>(pacc, pden, out);
  } else {
    attn_kernel_mono<<<B_ * (S_ / TI), 256, 0, stream>>>(x, f2, g2, w2, b2, out);
  }
}

// Round 3
// 58.499 us; speedup vs baseline: 1.5048x; 1.4851x over previous
//
#include <hip/hip_runtime.h>

// ConcatenationAttention: B=8, S=1024, H=128, A=16
// out[b,i,:] = sum_{j<i} w_ij * x[b,j,:],  w = softmax over j of
//   score(i,j) = sum_a w2[a]*tanh(f[b,i,a] + g[b,j,a] + b1[a]) + b2
//
// Round 3: wave-independent chunks (no barriers in main loop), raw v_exp_f32
// via __builtin_amdgcn_exp2f, packed PV via v_pk_fma_f32 + op_sel broadcast.

#define B_ 8
#define S_ 1024
#define H_ 128
#define A_ 16
#define TI 16
#define JC 64

typedef float f32x2 __attribute__((ext_vector_type(2)));

// acc += e2 * broadcast(x2.lo)
__device__ __forceinline__ void pk_fma_bl(f32x2& acc, f32x2 e2, f32x2 x2) {
  asm volatile("v_pk_fma_f32 %0, %1, %2, %0 op_sel:[0,0,0] op_sel_hi:[1,0,1]"
               : "+v"(acc) : "v"(e2), "v"(x2));
}
// acc += e2 * broadcast(x2.hi)
__device__ __forceinline__ void pk_fma_bh(f32x2& acc, f32x2 e2, f32x2 x2) {
  asm volatile("v_pk_fma_f32 %0, %1, %2, %0 op_sel:[0,1,0] op_sel_hi:[1,1,1]"
               : "+v"(acc) : "v"(e2), "v"(x2));
}

__global__ __launch_bounds__(256) void fg_kernel(
    const float* __restrict__ x, const float* __restrict__ W1,
    const float* __restrict__ b1, float* __restrict__ f2,
    float* __restrict__ g2) {
  int gid = blockIdx.x * 256 + threadIdx.x;   // B*S*32 threads
  int row = gid >> 5;                         // b*S + s
  int q = gid & 31;
  int a = q & 15;
  int half = q >> 4;
  const float4* x4 = reinterpret_cast<const float4*>(x + (size_t)row * H_);
  const float* w = W1 + half * H_ * A_ + a;   // column a, stride A_
  float s = 0.f;
#pragma unroll 4
  for (int hi = 0; hi < H_ / 4; ++hi) {
    float4 xv = x4[hi];
    s = fmaf(xv.x, w[(hi * 4 + 0) * A_], s);
    s = fmaf(xv.y, w[(hi * 4 + 1) * A_], s);
    s = fmaf(xv.z, w[(hi * 4 + 2) * A_], s);
    s = fmaf(xv.w, w[(hi * 4 + 3) * A_], s);
  }
  const float TANH_C = 2.8853900817779268f;   // 2*log2(e)
  if (half == 0)
    f2[row * A_ + a] = (s + b1[a]) * TANH_C;  // fold b1 into f
  else
    g2[row * A_ + a] = s * TANH_C;
}

// grid: B_*160 blocks of 4 waves; wave wv owns chunk wv of its 256-j segment.
__global__ __launch_bounds__(256, 5) void attn_part(
    const float* __restrict__ x, const float* __restrict__ f2,
    const float* __restrict__ g2, const float* __restrict__ w2,
    const float* __restrict__ b2, float* __restrict__ pacc,
    float* __restrict__ pden) {
  __shared__ __align__(16) float es[4][JC][A_];  // 16 KB: per-wave e + reduce scratch
  __shared__ float denw[4][16];

  const int tid = threadIdx.x;
  const int wv = tid >> 6;
  const int lane = tid & 63;
  const int bid = blockIdx.x;
  const int b = bid & 7;
  const int sidx = 159 - (bid >> 3);            // heavy segments first
  int t, s;
  if (sidx < 16)      { t = sidx;                             s = 0; }
  else if (sidx < 48) { int u = sidx - 16; t = 16 + (u >> 1); s = u & 1; }
  else if (sidx < 96) { int u = sidx - 48; t = 32 + u / 3;    s = u - (t - 32) * 3; }
  else                { int u = sidx - 96; t = 48 + (u >> 2); s = u & 3; }
  const int i0 = t << 4;
  const int jbase0 = s << 8;
  const int nch = min(4, (i0 + 15 - jbase0 + 63) >> 6);
  const int slot = (((b << 6) + t) << 2) + s;

  const float LOG2E = 1.4426950408889634f;
  float w2s[16];
  float K;
  {
    float sw = 0.f;
#pragma unroll
    for (int a = 0; a < 16; ++a) {
      float v = w2[a];
      w2s[a] = v * (2.f * LOG2E);
      sw += v;
    }
    K = (sw + b2[0]) * LOG2E;
  }

  const int i_e = lane & 15;
  const int jgrp = lane >> 4;
  const int th = lane >> 5;
  const int hq = lane & 31;

  float f_reg[16];
  {
    const float4* f4p =
        reinterpret_cast<const float4*>(f2 + (size_t)((b << 10) + i0 + i_e) * A_);
    float4 fa = f4p[0], fb = f4p[1], fc = f4p[2], fd = f4p[3];
    f_reg[0] = fa.x; f_reg[1] = fa.y; f_reg[2] = fa.z; f_reg[3] = fa.w;
    f_reg[4] = fb.x; f_reg[5] = fb.y; f_reg[6] = fb.z; f_reg[7] = fb.w;
    f_reg[8] = fc.x; f_reg[9] = fc.y; f_reg[10] = fc.z; f_reg[11] = fc.w;
    f_reg[12] = fd.x; f_reg[13] = fd.y; f_reg[14] = fd.z; f_reg[15] = fd.w;
  }

  union AccU { f32x2 a2[16]; float4 a4[8]; };  // [ip*4+h]
  AccU acc;
#pragma unroll
  for (int p = 0; p < 8; ++p) acc.a4[p] = make_float4(0.f, 0.f, 0.f, 0.f);
  float den = 0.f;

  const int jbase = jbase0 + (wv << 6);
  float* esw = &es[wv][0][0];

  if (wv < nch) {
    // ---- score phase: 16 j's per lane (rows jgrp*16..+15), no barriers ----
    const float4* gp4 = reinterpret_cast<const float4*>(
        g2 + ((size_t)((b << 10) + jbase + (jgrp << 4)) << 4));
    float* ew = esw + (jgrp << 8) + i_e;  // + k*16 floats (k*64B immediates)
    const int ilim = i0 + i_e;
    const int jrow0 = jbase + (jgrp << 4);
#pragma unroll 2
    for (int k = 0; k < 16; ++k) {
      float4 ga = gp4[k * 4 + 0], gb = gp4[k * 4 + 1];
      float4 gc = gp4[k * 4 + 2], gd = gp4[k * 4 + 3];
      float ps = 0.f;
#define TERM(idx, gcomp)                                                    \
  ps = fmaf(w2s[idx],                                                       \
            __builtin_amdgcn_rcpf(                                          \
                __builtin_amdgcn_exp2f(f_reg[idx] + gcomp) + 1.0f),         \
            ps);
      TERM(0, ga.x)  TERM(1, ga.y)  TERM(2, ga.z)  TERM(3, ga.w)
      TERM(4, gb.x)  TERM(5, gb.y)  TERM(6, gb.z)  TERM(7, gb.w)
      TERM(8, gc.x)  TERM(9, gc.y)  TERM(10, gc.z) TERM(11, gc.w)
      TERM(12, gd.x) TERM(13, gd.y) TERM(14, gd.z) TERM(15, gd.w)
#undef TERM
      float ev = (jrow0 + k < ilim) ? __builtin_amdgcn_exp2f(K - ps) : 0.f;
      ew[k << 4] = ev;
      den += ev;
    }
    den += __shfl_xor(den, 16);
    den += __shfl_xor(den, 32);

    // ---- PV: wave's own 64 j's, es broadcast reads, packed FMA ----
    const float4* esw4 = reinterpret_cast<const float4*>(esw);
    for (int blk = 0; blk < 8; ++blk) {
      const float4* xp = reinterpret_cast<const float4*>(
                             x + ((size_t)((b << 10) + jbase + (blk << 3)) << 7)) +
                         hq;
#pragma unroll
      for (int q = 0; q < 8; ++q) {
        const int jl = (blk << 3) + q;
        float4 xv = xp[q << 5];  // q*512B immediates
        union { float4 v4; f32x2 v2[2]; } ux, ua, ub;
        ux.v4 = xv;
        ua.v4 = esw4[(jl << 2) + (th << 1)];      // e rows th*8..+3
        ub.v4 = esw4[(jl << 2) + (th << 1) + 1];  // e rows th*8+4..+7
        pk_fma_bl(acc.a2[0], ua.v2[0], ux.v2[0]);
        pk_fma_bh(acc.a2[1], ua.v2[0], ux.v2[0]);
        pk_fma_bl(acc.a2[2], ua.v2[0], ux.v2[1]);
        pk_fma_bh(acc.a2[3], ua.v2[0], ux.v2[1]);
        pk_fma_bl(acc.a2[4], ua.v2[1], ux.v2[0]);
        pk_fma_bh(acc.a2[5], ua.v2[1], ux.v2[0]);
        pk_fma_bl(acc.a2[6], ua.v2[1], ux.v2[1]);
        pk_fma_bh(acc.a2[7], ua.v2[1], ux.v2[1]);
        pk_fma_bl(acc.a2[8], ub.v2[0], ux.v2[0]);
        pk_fma_bh(acc.a2[9], ub.v2[0], ux.v2[0]);
        pk_fma_bl(acc.a2[10], ub.v2[0], ux.v2[1]);
        pk_fma_bh(acc.a2[11], ub.v2[0], ux.v2[1]);
        pk_fma_bl(acc.a2[12], ub.v2[1], ux.v2[0]);
        pk_fma_bh(acc.a2[13], ub.v2[1], ux.v2[0]);
        pk_fma_bl(acc.a2[14], ub.v2[1], ux.v2[1]);
        pk_fma_bh(acc.a2[15], ub.v2[1], ux.v2[1]);
      }
    }
  }
  if (lane < 16) denw[wv][lane] = den;  // zeros for inactive waves

  // ---- cross-wave reduce: 4 -> 1 via es scratch (4 barriers total) ----
  float4* esall4 = reinterpret_cast<float4*>(&es[0][0][0]);
  __syncthreads();  // B0: all PV reads of es complete
  if (wv >= 2) {
#pragma unroll
    for (int p = 0; p < 8; ++p)
      esall4[((wv - 2) << 9) + (lane << 3) + p] = acc.a4[p];
  }
  __syncthreads();  // B1
  if (wv < 2) {
#pragma unroll
    for (int p = 0; p < 8; ++p) {
      float4 v = esall4[(wv << 9) + (lane << 3) + p];
      acc.a4[p].x += v.x; acc.a4[p].y += v.y;
      acc.a4[p].z += v.z; acc.a4[p].w += v.w;
    }
  }
  __syncthreads();  // B2
  if (wv == 1) {
#pragma unroll
    for (int p = 0; p < 8; ++p) esall4[(lane << 3) + p] = acc.a4[p];
  }
  __syncthreads();  // B3
  if (wv == 0) {
#pragma unroll
    for (int p = 0; p < 8; ++p) {
      float4 v = esall4[(lane << 3) + p];
      acc.a4[p].x += v.x; acc.a4[p].y += v.y;
      acc.a4[p].z += v.z; acc.a4[p].w += v.w;
    }
    float4* pacc4 = reinterpret_cast<float4*>(pacc);
#pragma unroll
    for (int ip = 0; ip < 4; ++ip) {
      const int row_e = (th << 3) + (ip << 1);
      float4 ve, vo;
      ve.x = acc.a2[ip * 4 + 0].x; ve.y = acc.a2[ip * 4 + 1].x;
      ve.z = acc.a2[ip * 4 + 2].x; ve.w = acc.a2[ip * 4 + 3].x;
      vo.x = acc.a2[ip * 4 + 0].y; vo.y = acc.a2[ip * 4 + 1].y;
      vo.z = acc.a2[ip * 4 + 2].y; vo.w = acc.a2[ip * 4 + 3].y;
      pacc4[(size_t)slot * 512 + (size_t)row_e * 32 + hq] = ve;
      pacc4[(size_t)slot * 512 + (size_t)(row_e + 1) * 32 + hq] = vo;
    }
    if (lane < 16)
      pden[slot * 16 + lane] =
          denw[0][lane] + denw[1][lane] + denw[2][lane] + denw[3][lane];
  }
}

__global__ __launch_bounds__(256) void combine_kernel(
    const float* __restrict__ pacc, const float* __restrict__ pden,
    float* __restrict__ out) {
  const int gid = blockIdx.x * 256 + threadIdx.x;  // B*S*32
  const int row = gid >> 5;
  const int hq = gid & 31;
  const int i = row & 1023;
  const int t = i >> 4;
  const int nseg = (t >> 4) + 1;
  const int slotbase = ((row >> 10) << 8) + (t << 2);  // ((b<<6)+t)<<2
  const float4* pacc4 = reinterpret_cast<const float4*>(pacc);
  float4 sum = make_float4(0.f, 0.f, 0.f, 0.f);
  float den = 0.f;
  for (int s = 0; s < nseg; ++s) {
    const int slot = slotbase + s;
    float4 v = pacc4[(size_t)slot * 512 + (size_t)(i & 15) * 32 + hq];
    sum.x += v.x; sum.y += v.y; sum.z += v.z; sum.w += v.w;
    den += pden[slot * 16 + (i & 15)];
  }
  const float dn = 1.0f / (den + 1e-10f);
  float4 o;
  o.x = sum.x * dn; o.y = sum.y * dn; o.z = sum.z * dn; o.w = sum.w * dn;
  reinterpret_cast<float4*>(out)[(size_t)row * 32 + hq] = o;
}

// ---------------- fallback: monolithic kernel (round 1, correct) ----------------
__global__ __launch_bounds__(256) void attn_kernel_mono(
    const float* __restrict__ x, const float* __restrict__ f2,
    const float* __restrict__ g2, const float* __restrict__ w2,
    const float* __restrict__ b2, float* __restrict__ out) {
  __shared__ __align__(16) float xs[JC * H_];
  __shared__ __align__(16) float gsm[JC * 18];
  __shared__ __align__(16) float es2[JC * A_];
  __shared__ float dpart[4][16];
  __shared__ float denom[TI];

  const int tid = threadIdx.x;
  const int bid = blockIdx.x;
  const int tile = (S_ / TI - 1) - (bid >> 3);
  const int b = bid & 7;
  const int i0 = tile * TI;

  const float LOG2E = 1.4426950408889634f;
  float w2s[16];
  float K;
  {
    float sw = 0.f;
#pragma unroll
    for (int a = 0; a < 16; ++a) {
      float v = w2[a];
      w2s[a] = v * (2.f * LOG2E);
      sw += v;
    }
    K = (sw + b2[0]) * LOG2E;
  }

  const int ti_e = tid & 15;
  const int jq = tid >> 4;
  float f_reg[16];
  {
    const float* frow = f2 + (size_t)((b << 10) + i0 + ti_e) * A_;
#pragma unroll
    for (int a = 0; a < 16; ++a) f_reg[a] = frow[a];
  }

  const int hc = tid & 31;
  const int jg = tid >> 5;
  float4 acc[TI];
#pragma unroll
  for (int t = 0; t < TI; ++t) acc[t] = make_float4(0.f, 0.f, 0.f, 0.f);
  if (tid < TI) denom[tid] = 0.f;

  const int nch = (i0 + TI - 1 + JC - 1) / JC;
  float4* xs4 = reinterpret_cast<float4*>(xs);
  const float4* es4 = reinterpret_cast<const float4*>(es2);
  const float4* xg4 = reinterpret_cast<const float4*>(x + (size_t)(b << 10) * H_);

  for (int c = 0; c < nch; ++c) {
    const int jbase = c * JC;
    __syncthreads();
    const float4* src = xg4 + jbase * (H_ / 4);
#pragma unroll
    for (int t = 0; t < 8; ++t) xs4[tid + 256 * t] = src[tid + 256 * t];
    {
      const float4* g4p =
          reinterpret_cast<const float4*>(g2 + (size_t)((b << 10) + jbase) * A_);
      float4 g4 = g4p[tid];
      float* dst = gsm + (tid >> 2) * 18 + (tid & 3) * 4;
      dst[0] = g4.x; dst[1] = g4.y; dst[2] = g4.z; dst[3] = g4.w;
    }
    __syncthreads();

    float partial = 0.f;
#pragma unroll
    for (int k = 0; k < 4; ++k) {
      const int jl = jq * 4 + k;
      const int j = jbase + jl;
      const float* grow = gsm + jl * 18;
      float ps = 0.f;
#pragma unroll
      for (int a = 0; a < 16; ++a) {
        float E = __builtin_amdgcn_exp2f(f_reg[a] + grow[a]);
        float r = __builtin_amdgcn_rcpf(E + 1.0f);
        ps = fmaf(w2s[a], r, ps);
      }
      float ev = (j < i0 + ti_e) ? __builtin_amdgcn_exp2f(K - ps) : 0.f;
      es2[jl * A_ + ti_e] = ev;
      partial += ev;
    }
    partial += __shfl_xor(partial, 16);
    partial += __shfl_xor(partial, 32);
    if ((tid & 63) < 16) dpart[tid >> 6][ti_e] = partial;
    __syncthreads();
    if (tid < 16)
      denom[tid] += dpart[0][tid] + dpart[1][tid] + dpart[2][tid] + dpart[3][tid];

#pragma unroll 2
    for (int jj = 0; jj < 8; ++jj) {
      const int jl = jg * 8 + jj;
      float4 xv = xs4[jl * (H_ / 4) + hc];
      float4 e0 = es4[jl * 4 + 0];
      float4 e1 = es4[jl * 4 + 1];
      float4 e2v = es4[jl * 4 + 2];
      float4 e3 = es4[jl * 4 + 3];
#define FMA4_(AC, sc)                \
  AC.x = fmaf(sc, xv.x, AC.x);       \
  AC.y = fmaf(sc, xv.y, AC.y);       \
  AC.z = fmaf(sc, xv.z, AC.z);       \
  AC.w = fmaf(sc, xv.w, AC.w)
      FMA4_(acc[0], e0.x);  FMA4_(acc[1], e0.y);
      FMA4_(acc[2], e0.z);  FMA4_(acc[3], e0.w);
      FMA4_(acc[4], e1.x);  FMA4_(acc[5], e1.y);
      FMA4_(acc[6], e1.z);  FMA4_(acc[7], e1.w);
      FMA4_(acc[8], e2v.x); FMA4_(acc[9], e2v.y);
      FMA4_(acc[10], e2v.z); FMA4_(acc[11], e2v.w);
      FMA4_(acc[12], e3.x); FMA4_(acc[13], e3.y);
      FMA4_(acc[14], e3.z); FMA4_(acc[15], e3.w);
#undef FMA4_
    }
  }

  __syncthreads();
  float4* red4 = xs4;
  if (jg >= 4) {
#pragma unroll
    for (int t = 0; t < TI; ++t) red4[((jg - 4) * TI + t) * 32 + hc] = acc[t];
  }
  __syncthreads();
  if (jg < 4) {
#pragma unroll
    for (int t = 0; t < TI; ++t) {
      float4 v = red4[(jg * TI + t) * 32 + hc];
      acc[t].x += v.x; acc[t].y += v.y; acc[t].z += v.z; acc[t].w += v.w;
    }
  }
  __syncthreads();
  if (jg == 2 || jg == 3) {
#pragma unroll
    for (int t = 0; t < TI; ++t) red4[((jg - 2) * TI + t) * 32 + hc] = acc[t];
  }
  __syncthreads();
  if (jg < 2) {
#pragma unroll
    for (int t = 0; t < TI; ++t) {
      float4 v = red4[(jg * TI + t) * 32 + hc];
      acc[t].x += v.x; acc[t].y += v.y; acc[t].z += v.z; acc[t].w += v.w;
    }
  }
  __syncthreads();
  if (jg == 1) {
#pragma unroll
    for (int t = 0; t < TI; ++t) red4[t * 32 + hc] = acc[t];
  }
  __syncthreads();
  if (jg == 0) {
    float4* out4 = reinterpret_cast<float4*>(out);
#pragma unroll
    for (int t = 0; t < TI; ++t) {
      float4 v = red4[t * 32 + hc];
      float dn = 1.0f / (denom[t] + 1e-10f);
      float4 o;
      o.x = (acc[t].x + v.x) * dn;
      o.y = (acc[t].y + v.y) * dn;
      o.z = (acc[t].z + v.z) * dn;
      o.w = (acc[t].w + v.w) * dn;
      out4[(size_t)((b << 10) + i0 + t) * 32 + hc] = o;
    }
  }
}

extern "C" void kernel_launch(void* const* d_in, const int* in_sizes, int n_in,
                              void* d_out, int out_size, void* d_ws,
                              size_t ws_size, hipStream_t stream) {
  (void)in_sizes; (void)n_in; (void)out_size;
  const float* x  = (const float*)d_in[0];
  const float* W1 = (const float*)d_in[1];
  const float* b1 = (const float*)d_in[2];
  const float* w2 = (const float*)d_in[3];
  const float* b2 = (const float*)d_in[4];
  float* out = (float*)d_out;

  float* f2 = (float*)d_ws;                  // [B*S, A]
  float* g2 = f2 + (size_t)B_ * S_ * A_;     // [B*S, A]
  float* pacc = g2 + (size_t)B_ * S_ * A_;   // [2048 slots][16][128]
  float* pden = pacc + (size_t)2048 * 2048;  // [2048 slots][16]

  const size_t need_bytes =
      ((size_t)B_ * S_ * A_ * 2 + (size_t)2048 * 2048 + (size_t)2048 * 16) *
      sizeof(float);

  fg_kernel<<<(B_ * S_ * 32) / 256, 256, 0, stream>>>(x, W1, b1, f2, g2);
  if (ws_size >= need_bytes) {
    attn_part<<<B_ * 160, 256, 0, stream>>>(x, f2, g2, w2, b2, pacc, pden);
    combine_kernel<<<(B_ * S_ * 32) / 256, 256, 0, stream>>>(pacc, pden, out);
  } else {
    attn_kernel_mono<<<B_ * (S_ / TI), 256, 0, stream>>>(x, f2, g2, w2, b2, out);
  }
}

// Round 4
// 55.287 us; speedup vs baseline: 1.5922x; 1.0581x over previous
//
#include <hip/hip_runtime.h>

// ConcatenationAttention: B=8, S=1024, H=128, A=16
// out[b,i,:] = sum_{j<i} w_ij * x[b,j,:],  w = softmax over j of
//   score(i,j) = sum_a w2[a]*tanh(f[b,i,a] + g[b,j,a] + b1[a]) + b2
//
// Round 4: score phase remapped lane=j: g row held in VGPRs (loaded once),
// f row via wave-uniform scalar loads (prefetchable), ev -> LDS via swizzled
// ds_write_b128. PV / reduce / combine unchanged from round 3.

#define B_ 8
#define S_ 1024
#define H_ 128
#define A_ 16
#define TI 16
#define JC 64

typedef float f32x2 __attribute__((ext_vector_type(2)));

// acc += e2 * broadcast(x2.lo)
__device__ __forceinline__ void pk_fma_bl(f32x2& acc, f32x2 e2, f32x2 x2) {
  asm volatile("v_pk_fma_f32 %0, %1, %2, %0 op_sel:[0,0,0] op_sel_hi:[1,0,1]"
               : "+v"(acc) : "v"(e2), "v"(x2));
}
// acc += e2 * broadcast(x2.hi)
__device__ __forceinline__ void pk_fma_bh(f32x2& acc, f32x2 e2, f32x2 x2) {
  asm volatile("v_pk_fma_f32 %0, %1, %2, %0 op_sel:[0,1,0] op_sel_hi:[1,1,1]"
               : "+v"(acc) : "v"(e2), "v"(x2));
}

__global__ __launch_bounds__(256) void fg_kernel(
    const float* __restrict__ x, const float* __restrict__ W1,
    const float* __restrict__ b1, float* __restrict__ f2,
    float* __restrict__ g2) {
  int gid = blockIdx.x * 256 + threadIdx.x;   // B*S*32 threads
  int row = gid >> 5;                         // b*S + s
  int q = gid & 31;
  int a = q & 15;
  int half = q >> 4;
  const float4* x4 = reinterpret_cast<const float4*>(x + (size_t)row * H_);
  const float* w = W1 + half * H_ * A_ + a;   // column a, stride A_
  float s = 0.f;
#pragma unroll 4
  for (int hi = 0; hi < H_ / 4; ++hi) {
    float4 xv = x4[hi];
    s = fmaf(xv.x, w[(hi * 4 + 0) * A_], s);
    s = fmaf(xv.y, w[(hi * 4 + 1) * A_], s);
    s = fmaf(xv.z, w[(hi * 4 + 2) * A_], s);
    s = fmaf(xv.w, w[(hi * 4 + 3) * A_], s);
  }
  const float TANH_C = 2.8853900817779268f;   // 2*log2(e)
  if (half == 0)
    f2[row * A_ + a] = (s + b1[a]) * TANH_C;  // fold b1 into f
  else
    g2[row * A_ + a] = s * TANH_C;
}

// grid: B_*160 blocks of 4 waves; wave wv owns chunk wv of its 256-j segment.
__global__ __launch_bounds__(256, 5) void attn_part(
    const float* __restrict__ x, const float* __restrict__ f2,
    const float* __restrict__ g2, const float* __restrict__ w2,
    const float* __restrict__ b2, float* __restrict__ pacc,
    float* __restrict__ pden) {
  // es[wv]: e stored [j][i-quad swizzled], 4 KB per wave; doubles as reduce scratch
  __shared__ __align__(16) float es[4][1024];
  __shared__ float denw[4][16];

  const int tid = threadIdx.x;
  const int wv = tid >> 6;
  const int lane = tid & 63;
  const int bid = blockIdx.x;
  const int b = bid & 7;
  const int sidx = 159 - (bid >> 3);            // heavy segments first
  int t, s;
  if (sidx < 16)      { t = sidx;                             s = 0; }
  else if (sidx < 48) { int u = sidx - 16; t = 16 + (u >> 1); s = u & 1; }
  else if (sidx < 96) { int u = sidx - 48; t = 32 + u / 3;    s = u - (t - 32) * 3; }
  else                { int u = sidx - 96; t = 48 + (u >> 2); s = u & 3; }
  const int i0 = t << 4;
  const int jbase0 = s << 8;
  const int nch = min(4, (i0 + 15 - jbase0 + 63) >> 6);
  const int slot = (((b << 6) + t) << 2) + s;

  const float LOG2E = 1.4426950408889634f;
  float w2s[16];
  float K;
  {
    float sw = 0.f;
#pragma unroll
    for (int a = 0; a < 16; ++a) {
      float v = w2[a];
      w2s[a] = v * (2.f * LOG2E);
      sw += v;
    }
    K = (sw + b2[0]) * LOG2E;
  }

  const int th = lane >> 5;
  const int hq = lane & 31;
  const int jbase = jbase0 + (wv << 6);
  float* esw = &es[wv][0];
  float4* esw4w = reinterpret_cast<float4*>(esw);
  const float4* esw4 = reinterpret_cast<const float4*>(esw);

  union AccU { f32x2 a2[16]; float4 a4[8]; };  // [ip*4+h]
  AccU acc;
#pragma unroll
  for (int p = 0; p < 8; ++p) acc.a4[p] = make_float4(0.f, 0.f, 0.f, 0.f);
  float dsum = 0.f;

  if (wv < nch) {
    const int j = lane;  // score mapping: lane owns column j
    // g row -> 16 VGPRs, loaded ONCE per chunk
    const float4* gp4 = reinterpret_cast<const float4*>(
        g2 + ((size_t)((b << 10) + jbase + j) << 4));
    float4 ga = gp4[0], gb = gp4[1], gc = gp4[2], gd = gp4[3];
    float gr[16] = {ga.x, ga.y, ga.z, ga.w, gb.x, gb.y, gb.z, gb.w,
                    gc.x, gc.y, gc.z, gc.w, gd.x, gd.y, gd.z, gd.w};
    // f rows are wave-uniform -> scalar loads, prefetched by compiler
    const float* fbase = f2 + ((size_t)((b << 10) + i0) << 4);
    const int jglob = jbase + j;
    const int jswz = (j << 2);
    const int jm3 = j & 3;

#pragma unroll
    for (int q = 0; q < 4; ++q) {
      float evq[4];
#pragma unroll
      for (int u = 0; u < 4; ++u) {
        const int i = (q << 2) + u;
        const float* fr = fbase + (i << 4);
        float ps = 0.f;
#define TERM(idx)                                                        \
  ps = fmaf(w2s[idx],                                                    \
            __builtin_amdgcn_rcpf(                                       \
                __builtin_amdgcn_exp2f(fr[idx] + gr[idx]) + 1.0f),       \
            ps);
        TERM(0)  TERM(1)  TERM(2)  TERM(3)
        TERM(4)  TERM(5)  TERM(6)  TERM(7)
        TERM(8)  TERM(9)  TERM(10) TERM(11)
        TERM(12) TERM(13) TERM(14) TERM(15)
#undef TERM
        evq[u] = (jglob < i0 + i) ? __builtin_amdgcn_exp2f(K - ps) : 0.f;
      }
      float4 w4;
      w4.x = evq[0]; w4.y = evq[1]; w4.z = evq[2]; w4.w = evq[3];
      esw4w[jswz + (q ^ jm3)] = w4;   // swizzled transpose write
    }

    // ---- denom: lane (part, ie) sums es[j = part*16 + jj][ie] ----
    {
      const int ie = lane & 15;
      const int part = lane >> 4;
      const int iq = ie >> 2, ir = ie & 3;
#pragma unroll
      for (int jj = 0; jj < 16; ++jj) {
        const int jr = (part << 4) + jj;
        dsum += esw[(jr << 4) + ((iq ^ (jr & 3)) << 2) + ir];
      }
      dsum += __shfl_xor(dsum, 16);
      dsum += __shfl_xor(dsum, 32);
    }

    // ---- PV: wave's own 64 j's, es broadcast reads, packed FMA ----
    for (int blk = 0; blk < 8; ++blk) {
      const float4* xp = reinterpret_cast<const float4*>(
                             x + ((size_t)((b << 10) + jbase + (blk << 3)) << 7)) +
                         hq;
      float4 xv[8];
#pragma unroll
      for (int r = 0; r < 8; ++r) xv[r] = xp[r << 5];  // r*512B immediates
#pragma unroll
      for (int r = 0; r < 8; ++r) {
        const int jl = (blk << 3) + r;
        const int base = jl << 2;
        const int sw = jl & 3;
        union { float4 v4; f32x2 v2[2]; } ux, ua, ub;
        ux.v4 = xv[r];
        ua.v4 = esw4[base + ((th << 1) ^ sw)];        // e[th*8..+3][jl]
        ub.v4 = esw4[base + (((th << 1) | 1) ^ sw)];  // e[th*8+4..+7][jl]
        pk_fma_bl(acc.a2[0], ua.v2[0], ux.v2[0]);
        pk_fma_bh(acc.a2[1], ua.v2[0], ux.v2[0]);
        pk_fma_bl(acc.a2[2], ua.v2[0], ux.v2[1]);
        pk_fma_bh(acc.a2[3], ua.v2[0], ux.v2[1]);
        pk_fma_bl(acc.a2[4], ua.v2[1], ux.v2[0]);
        pk_fma_bh(acc.a2[5], ua.v2[1], ux.v2[0]);
        pk_fma_bl(acc.a2[6], ua.v2[1], ux.v2[1]);
        pk_fma_bh(acc.a2[7], ua.v2[1], ux.v2[1]);
        pk_fma_bl(acc.a2[8], ub.v2[0], ux.v2[0]);
        pk_fma_bh(acc.a2[9], ub.v2[0], ux.v2[0]);
        pk_fma_bl(acc.a2[10], ub.v2[0], ux.v2[1]);
        pk_fma_bh(acc.a2[11], ub.v2[0], ux.v2[1]);
        pk_fma_bl(acc.a2[12], ub.v2[1], ux.v2[0]);
        pk_fma_bh(acc.a2[13], ub.v2[1], ux.v2[0]);
        pk_fma_bl(acc.a2[14], ub.v2[1], ux.v2[1]);
        pk_fma_bh(acc.a2[15], ub.v2[1], ux.v2[1]);
      }
    }
  }
  if (lane < 16) denw[wv][lane] = dsum;  // zeros for inactive waves

  // ---- cross-wave reduce: 4 -> 1 via es scratch (4 barriers total) ----
  float4* esall4 = reinterpret_cast<float4*>(&es[0][0]);
  __syncthreads();  // B0: all PV reads of es complete
  if (wv >= 2) {
#pragma unroll
    for (int p = 0; p < 8; ++p)
      esall4[((wv - 2) << 9) + (lane << 3) + p] = acc.a4[p];
  }
  __syncthreads();  // B1
  if (wv < 2) {
#pragma unroll
    for (int p = 0; p < 8; ++p) {
      float4 v = esall4[(wv << 9) + (lane << 3) + p];
      acc.a4[p].x += v.x; acc.a4[p].y += v.y;
      acc.a4[p].z += v.z; acc.a4[p].w += v.w;
    }
  }
  __syncthreads();  // B2
  if (wv == 1) {
#pragma unroll
    for (int p = 0; p < 8; ++p) esall4[(lane << 3) + p] = acc.a4[p];
  }
  __syncthreads();  // B3
  if (wv == 0) {
#pragma unroll
    for (int p = 0; p < 8; ++p) {
      float4 v = esall4[(lane << 3) + p];
      acc.a4[p].x += v.x; acc.a4[p].y += v.y;
      acc.a4[p].z += v.z; acc.a4[p].w += v.w;
    }
    float4* pacc4 = reinterpret_cast<float4*>(pacc);
#pragma unroll
    for (int ip = 0; ip < 4; ++ip) {
      const int row_e = (th << 3) + (ip << 1);
      float4 ve, vo;
      ve.x = acc.a2[ip * 4 + 0].x; ve.y = acc.a2[ip * 4 + 1].x;
      ve.z = acc.a2[ip * 4 + 2].x; ve.w = acc.a2[ip * 4 + 3].x;
      vo.x = acc.a2[ip * 4 + 0].y; vo.y = acc.a2[ip * 4 + 1].y;
      vo.z = acc.a2[ip * 4 + 2].y; vo.w = acc.a2[ip * 4 + 3].y;
      pacc4[(size_t)slot * 512 + (size_t)row_e * 32 + hq] = ve;
      pacc4[(size_t)slot * 512 + (size_t)(row_e + 1) * 32 + hq] = vo;
    }
    if (lane < 16)
      pden[slot * 16 + lane] =
          denw[0][lane] + denw[1][lane] + denw[2][lane] + denw[3][lane];
  }
}

__global__ __launch_bounds__(256) void combine_kernel(
    const float* __restrict__ pacc, const float* __restrict__ pden,
    float* __restrict__ out) {
  const int gid = blockIdx.x * 256 + threadIdx.x;  // B*S*32
  const int row = gid >> 5;
  const int hq = gid & 31;
  const int i = row & 1023;
  const int t = i >> 4;
  const int nseg = (t >> 4) + 1;
  const int slotbase = ((row >> 10) << 8) + (t << 2);  // ((b<<6)+t)<<2
  const float4* pacc4 = reinterpret_cast<const float4*>(pacc);
  float4 sum = make_float4(0.f, 0.f, 0.f, 0.f);
  float den = 0.f;
  for (int s = 0; s < nseg; ++s) {
    const int slot = slotbase + s;
    float4 v = pacc4[(size_t)slot * 512 + (size_t)(i & 15) * 32 + hq];
    sum.x += v.x; sum.y += v.y; sum.z += v.z; sum.w += v.w;
    den += pden[slot * 16 + (i & 15)];
  }
  const float dn = 1.0f / (den + 1e-10f);
  float4 o;
  o.x = sum.x * dn; o.y = sum.y * dn; o.z = sum.z * dn; o.w = sum.w * dn;
  reinterpret_cast<float4*>(out)[(size_t)row * 32 + hq] = o;
}

// ---------------- fallback: monolithic kernel (round 1, correct) ----------------
__global__ __launch_bounds__(256) void attn_kernel_mono(
    const float* __restrict__ x, const float* __restrict__ f2,
    const float* __restrict__ g2, const float* __restrict__ w2,
    const float* __restrict__ b2, float* __restrict__ out) {
  __shared__ __align__(16) float xs[JC * H_];
  __shared__ __align__(16) float gsm[JC * 18];
  __shared__ __align__(16) float es2[JC * A_];
  __shared__ float dpart[4][16];
  __shared__ float denom[TI];

  const int tid = threadIdx.x;
  const int bid = blockIdx.x;
  const int tile = (S_ / TI - 1) - (bid >> 3);
  const int b = bid & 7;
  const int i0 = tile * TI;

  const float LOG2E = 1.4426950408889634f;
  float w2s[16];
  float K;
  {
    float sw = 0.f;
#pragma unroll
    for (int a = 0; a < 16; ++a) {
      float v = w2[a];
      w2s[a] = v * (2.f * LOG2E);
      sw += v;
    }
    K = (sw + b2[0]) * LOG2E;
  }

  const int ti_e = tid & 15;
  const int jq = tid >> 4;
  float f_reg[16];
  {
    const float* frow = f2 + (size_t)((b << 10) + i0 + ti_e) * A_;
#pragma unroll
    for (int a = 0; a < 16; ++a) f_reg[a] = frow[a];
  }

  const int hc = tid & 31;
  const int jg = tid >> 5;
  float4 acc[TI];
#pragma unroll
  for (int t = 0; t < TI; ++t) acc[t] = make_float4(0.f, 0.f, 0.f, 0.f);
  if (tid < TI) denom[tid] = 0.f;

  const int nch = (i0 + TI - 1 + JC - 1) / JC;
  float4* xs4 = reinterpret_cast<float4*>(xs);
  const float4* es4 = reinterpret_cast<const float4*>(es2);
  const float4* xg4 = reinterpret_cast<const float4*>(x + (size_t)(b << 10) * H_);

  for (int c = 0; c < nch; ++c) {
    const int jbase = c * JC;
    __syncthreads();
    const float4* src = xg4 + jbase * (H_ / 4);
#pragma unroll
    for (int t = 0; t < 8; ++t) xs4[tid + 256 * t] = src[tid + 256 * t];
    {
      const float4* g4p =
          reinterpret_cast<const float4*>(g2 + (size_t)((b << 10) + jbase) * A_);
      float4 g4 = g4p[tid];
      float* dst = gsm + (tid >> 2) * 18 + (tid & 3) * 4;
      dst[0] = g4.x; dst[1] = g4.y; dst[2] = g4.z; dst[3] = g4.w;
    }
    __syncthreads();

    float partial = 0.f;
#pragma unroll
    for (int k = 0; k < 4; ++k) {
      const int jl = jq * 4 + k;
      const int j = jbase + jl;
      const float* grow = gsm + jl * 18;
      float ps = 0.f;
#pragma unroll
      for (int a = 0; a < 16; ++a) {
        float E = __builtin_amdgcn_exp2f(f_reg[a] + grow[a]);
        float r = __builtin_amdgcn_rcpf(E + 1.0f);
        ps = fmaf(w2s[a], r, ps);
      }
      float ev = (j < i0 + ti_e) ? __builtin_amdgcn_exp2f(K - ps) : 0.f;
      es2[jl * A_ + ti_e] = ev;
      partial += ev;
    }
    partial += __shfl_xor(partial, 16);
    partial += __shfl_xor(partial, 32);
    if ((tid & 63) < 16) dpart[tid >> 6][ti_e] = partial;
    __syncthreads();
    if (tid < 16)
      denom[tid] += dpart[0][tid] + dpart[1][tid] + dpart[2][tid] + dpart[3][tid];

#pragma unroll 2
    for (int jj = 0; jj < 8; ++jj) {
      const int jl = jg * 8 + jj;
      float4 xv = xs4[jl * (H_ / 4) + hc];
      float4 e0 = es4[jl * 4 + 0];
      float4 e1 = es4[jl * 4 + 1];
      float4 e2v = es4[jl * 4 + 2];
      float4 e3 = es4[jl * 4 + 3];
#define FMA4_(AC, sc)                \
  AC.x = fmaf(sc, xv.x, AC.x);       \
  AC.y = fmaf(sc, xv.y, AC.y);       \
  AC.z = fmaf(sc, xv.z, AC.z);       \
  AC.w = fmaf(sc, xv.w, AC.w)
      FMA4_(acc[0], e0.x);  FMA4_(acc[1], e0.y);
      FMA4_(acc[2], e0.z);  FMA4_(acc[3], e0.w);
      FMA4_(acc[4], e1.x);  FMA4_(acc[5], e1.y);
      FMA4_(acc[6], e1.z);  FMA4_(acc[7], e1.w);
      FMA4_(acc[8], e2v.x); FMA4_(acc[9], e2v.y);
      FMA4_(acc[10], e2v.z); FMA4_(acc[11], e2v.w);
      FMA4_(acc[12], e3.x); FMA4_(acc[13], e3.y);
      FMA4_(acc[14], e3.z); FMA4_(acc[15], e3.w);
#undef FMA4_
    }
  }

  __syncthreads();
  float4* red4 = xs4;
  if (jg >= 4) {
#pragma unroll
    for (int t = 0; t < TI; ++t) red4[((jg - 4) * TI + t) * 32 + hc] = acc[t];
  }
  __syncthreads();
  if (jg < 4) {
#pragma unroll
    for (int t = 0; t < TI; ++t) {
      float4 v = red4[(jg * TI + t) * 32 + hc];
      acc[t].x += v.x; acc[t].y += v.y; acc[t].z += v.z; acc[t].w += v.w;
    }
  }
  __syncthreads();
  if (jg == 2 || jg == 3) {
#pragma unroll
    for (int t = 0; t < TI; ++t) red4[((jg - 2) * TI + t) * 32 + hc] = acc[t];
  }
  __syncthreads();
  if (jg < 2) {
#pragma unroll
    for (int t = 0; t < TI; ++t) {
      float4 v = red4[(jg * TI + t) * 32 + hc];
      acc[t].x += v.x; acc[t].y += v.y; acc[t].z += v.z; acc[t].w += v.w;
    }
  }
  __syncthreads();
  if (jg == 1) {
#pragma unroll
    for (int t = 0; t < TI; ++t) red4[t * 32 + hc] = acc[t];
  }
  __syncthreads();
  if (jg == 0) {
    float4* out4 = reinterpret_cast<float4*>(out);
#pragma unroll
    for (int t = 0; t < TI; ++t) {
      float4 v = red4[t * 32 + hc];
      float dn = 1.0f / (denom[t] + 1e-10f);
      float4 o;
      o.x = (acc[t].x + v.x) * dn;
      o.y = (acc[t].y + v.y) * dn;
      o.z = (acc[t].z + v.z) * dn;
      o.w = (acc[t].w + v.w) * dn;
      out4[(size_t)((b << 10) + i0 + t) * 32 + hc] = o;
    }
  }
}

extern "C" void kernel_launch(void* const* d_in, const int* in_sizes, int n_in,
                              void* d_out, int out_size, void* d_ws,
                              size_t ws_size, hipStream_t stream) {
  (void)in_sizes; (void)n_in; (void)out_size;
  const float* x  = (const float*)d_in[0];
  const float* W1 = (const float*)d_in[1];
  const float* b1 = (const float*)d_in[2];
  const float* w2 = (const float*)d_in[3];
  const float* b2 = (const float*)d_in[4];
  float* out = (float*)d_out;

  float* f2 = (float*)d_ws;                  // [B*S, A]
  float* g2 = f2 + (size_t)B_ * S_ * A_;     // [B*S, A]
  float* pacc = g2 + (size_t)B_ * S_ * A_;   // [2048 slots][16][128]
  float* pden = pacc + (size_t)2048 * 2048;  // [2048 slots][16]

  const size_t need_bytes =
      ((size_t)B_ * S_ * A_ * 2 + (size_t)2048 * 2048 + (size_t)2048 * 16) *
      sizeof(float);

  fg_kernel<<<(B_ * S_ * 32) / 256, 256, 0, stream>>>(x, W1, b1, f2, g2);
  if (ws_size >= need_bytes) {
    attn_part<<<B_ * 160, 256, 0, stream>>>(x, f2, g2, w2, b2, pacc, pden);
    combine_kernel<<<(B_ * S_ * 32) / 256, 256, 0, stream>>>(pacc, pden, out);
  } else {
    attn_kernel_mono<<<B_ * (S_ / TI), 256, 0, stream>>>(x, f2, g2, w2, b2, out);
  }
}